// Round 10
// baseline (2578.408 us; speedup 1.0000x reference)
//
#include <hip/hip_runtime.h>

// GIN 2-layer via linearity:
//   z1 = (I+A)x ; hid = z1@W1^T + b1
//   z2 = (I+A)z1 ; out = z2@(W2W1)^T + (1+deg)*(W2b1) + b2
// Round 9 (resubmit; R9 bench was an infra failure): A measured ~150us
// (storm of 563K contended global atomics); B1's CSR phase ~16us exists
// only to enable gather-style agg.
// -> accumulate-style agg: per-edge wave-wide gather + LDS fp32 atomicAdd
//    into acc[64][129]; no esrc/rpse anywhere; deg from staging hist.
// -> scatter back to 391 coarse buckets (storm /3.7); B filters its quarter
//    during LDS staging.

#define DFEAT 128
#define BSHIFT 8
#define NB_MAX 512
#define CAP 8192    // coarse bucket capacity (256 nodes, mean 4096)
#define LROWS 136   // bf16 LDS tile row stride (shorts)
#define ACCW 129    // fp32 accumulator row stride (floats) - bank spread
#define ESCAP 2048  // per-64-node-block edge capacity (mean 1024, 32-sigma)

typedef __attribute__((ext_vector_type(8))) short short8;
typedef __attribute__((ext_vector_type(4))) float f32x4;

__device__ __forceinline__ float bf2f(unsigned short u) {
    union { unsigned int i; float f; } c;
    c.i = ((unsigned int)u) << 16;
    return c.f;
}
__device__ __forceinline__ unsigned short f2b(float f) {
    union { float f; unsigned int i; } c;
    c.f = f;
    unsigned int u = c.i;
    u = (u + 0x7FFFu + ((u >> 16) & 1u)) >> 16;   // RNE
    return (unsigned short)u;
}

// ---------------- kernel A: edge scatter + cast + weight prep ----------------
// blocks [0,nscat): radix-bucket scatter, encode (src<<8)|(dst&255).
// blocks [nscat,nscat+64): weight prep. rest: x -> bf16 cast (+ zero row n).

__global__ __launch_bounds__(256) void scatter_cast_prep(
        const int* __restrict__ src, const int* __restrict__ dst,
        int* __restrict__ bcur, int* __restrict__ ebuf, int E, int nscat, int nbk,
        const float* __restrict__ x, unsigned short* __restrict__ xb,
        int total4, int nzero,
        const float* __restrict__ W1, const float* __restrict__ W2,
        const float* __restrict__ b1, unsigned short* __restrict__ Wb1,
        unsigned short* __restrict__ Wcb, float* __restrict__ w2b1) {
    int tid = threadIdx.x;
    if (blockIdx.x >= nscat + 64) {
        int i = (blockIdx.x - nscat - 64) * 256 + tid;
        if (i < total4) {
            float4 v = ((const float4*)x)[i];
            ushort4 o;
            o.x = f2b(v.x); o.y = f2b(v.y); o.z = f2b(v.z); o.w = f2b(v.w);
            ((ushort4*)xb)[i] = o;
        }
        if (blockIdx.x == nscat + 64 && tid < 32)   // zero-row at index nzero
            ((ushort4*)xb)[(size_t)nzero * 32 + tid] = make_ushort4(0, 0, 0, 0);
        return;
    }
    if (blockIdx.x >= nscat) {
        __shared__ float red[256];
        int bb = blockIdx.x - nscat;
        int i = bb * 2 + (tid >> 7);
        int j = tid & 127;
        float s = 0.f;
        #pragma unroll 4
        for (int k = 0; k < 128; k++) s += W2[i * 128 + k] * W1[k * 128 + j];
        Wcb[i * 128 + j] = f2b(s);
        Wb1[i * 128 + j] = f2b(W1[i * 128 + j]);
        red[tid] = W2[i * 128 + j] * b1[j];
        __syncthreads();
        if (j == 0) {
            float t = 0.f;
            for (int k = 0; k < 128; k++) t += red[tid + k];
            w2b1[i] = t;
        }
        return;
    }
    __shared__ int lh[NB_MAX];
    for (int i = tid; i < nbk; i += 256) lh[i] = 0;
    __syncthreads();
    int e0 = blockIdx.x * 4096;
    int e1 = min(e0 + 4096, E);
    int s[16], d[16];
    #pragma unroll
    for (int j = 0; j < 16; j++) {
        int e = e0 + tid + 256 * j;
        if (e < e1) { s[j] = src[e]; d[j] = dst[e]; atomicAdd(&lh[d[j] >> BSHIFT], 1); }
    }
    __syncthreads();
    for (int i = tid; i < nbk; i += 256) {
        int c = lh[i];
        lh[i] = c ? (i * CAP + atomicAdd(&bcur[i], c)) : 0;  // absolute base
    }
    __syncthreads();
    #pragma unroll
    for (int j = 0; j < 16; j++) {
        int e = e0 + tid + 256 * j;
        if (e < e1) {
            int b = d[j] >> BSHIFT;
            int p = atomicAdd(&lh[b], 1);
            if (p < (b + 1) * CAP) ebuf[p] = (s[j] << 8) | (d[j] & 255);
        }
    }
}

// ---------------- accumulate-style fused agg + GEMM ----------------
// Block = 64 nodes = quarter (b&3) of coarse bucket (b>>2).
// Phase 0: init acc[64][129] fp32 with self rows.
// Phase 1: stage quarter's edges from ebuf into LDS (+deg hist), pad to 32.
// Phase 2: one edge per wave iteration: lane l gathers dword l of row src
//          (coalesced 256B), 2x LDS atomicAdd into acc[d]. 8 edges unrolled.
// Phase 3: acc -> bf16 (f2b) -> lt (aliases acc) [+ z1 global for layer 1].
// Phase 4: MFMA 64-row tile, wave w -> col-blocks {2w,2w+1}.

__global__ __launch_bounds__(256) void fused_agg_gemm1(
        const int* __restrict__ ebuf, const int* __restrict__ bcur,
        const ushort4* __restrict__ zin4, const unsigned short* __restrict__ Wb,
        const float* __restrict__ bias, unsigned short* __restrict__ zout,
        float* __restrict__ out, int n) {
    __shared__ __align__(16) float acc[64 * ACCW];   // 33 KB; lt aliases
    __shared__ int ebuf_s[ESCAP];
    __shared__ int deg_s[64];
    __shared__ int scur;
    short* lt = (short*)acc;

    int tid = threadIdx.x;
    int b = blockIdx.x;
    int cb = b >> 2, qq = b & 3;
    int e0 = cb * CAP;
    int cnt = min(bcur[cb], CAP);
    const char* zb = (const char*)zin4;

    if (b == 0 && tid < 16) {   // zero-row in z1 for layer-2 pad gathers
        short8 z8 = {0, 0, 0, 0, 0, 0, 0, 0};
        *(short8*)((char*)zout + (unsigned)n * 256u + tid * 16) = z8;
    }

    // phase 0: init acc with self rows
    {
        int r = tid >> 2, c = tid & 3;
        int node = b * 64 + r;
        float* ar = acc + r * ACCW + c * 32;
        if (node < n) {
            const short8* xp = (const short8*)(zb + (size_t)node * 256u + (unsigned)c * 64u);
            #pragma unroll
            for (int v = 0; v < 4; v++) {
                short8 u = xp[v];
                #pragma unroll
                for (int t2 = 0; t2 < 8; t2++) ar[v * 8 + t2] = bf2f((unsigned short)u[t2]);
            }
        } else {
            #pragma unroll
            for (int i = 0; i < 32; i++) ar[i] = 0.f;
        }
    }
    if (tid < 64) deg_s[tid] = 0;
    if (tid == 0) scur = 0;
    __syncthreads();

    // phase 1: stage + filter quarter + deg hist
    for (int e = tid; e < cnt; e += 256) {
        int code = ebuf[e0 + e];
        if (((code >> 6) & 3) == qq) {
            int p = atomicAdd(&scur, 1);
            if (p < ESCAP) {
                ebuf_s[p] = code;
                atomicAdd(&deg_s[code & 63], 1);
            }
        }
    }
    __syncthreads();
    int kept = min(scur, ESCAP);
    int kp = (kept + 31) & ~31;
    for (int i = kept + tid; i < kp; i += 256) ebuf_s[i] = (n << 8);  // pad: s=n,d=0
    __syncthreads();

    // phase 2: edge loop, one edge per wave, 8 unrolled
    int w = tid >> 6, l = tid & 63;
    unsigned lby = (unsigned)l * 4u;
    for (int base = w * 8; base < kp; base += 32) {
        int code[8]; unsigned val[8];
        #pragma unroll
        for (int j = 0; j < 8; j++) code[j] = ebuf_s[base + j];
        #pragma unroll
        for (int j = 0; j < 8; j++) {
            unsigned off = (((unsigned)code[j]) >> 8) * 256u + lby;
            val[j] = *(const unsigned*)(zb + off);
        }
        #pragma unroll
        for (int j = 0; j < 8; j++) {
            int d = code[j] & 63;
            float* ap2 = acc + d * ACCW + 2 * l;
            union { unsigned u; float f; } lo, hi;
            lo.u = val[j] << 16;
            hi.u = val[j] & 0xffff0000u;
            atomicAdd(ap2, lo.f);
            atomicAdd(ap2 + 1, hi.f);
        }
    }
    __syncthreads();

    // phase 3: acc -> bf16, write z1 global + lt (lt aliases acc)
    {
        int r = tid >> 2, c = tid & 3;
        float fv[32];
        const float* ar = acc + r * ACCW + c * 32;
        #pragma unroll
        for (int i = 0; i < 32; i++) fv[i] = ar[i];
        __syncthreads();   // all acc reads done before lt overlay
        short8 o4[4];
        #pragma unroll
        for (int v = 0; v < 4; v++) {
            #pragma unroll
            for (int t2 = 0; t2 < 8; t2++) o4[v][t2] = (short)f2b(fv[v * 8 + t2]);
            *(short8*)(lt + r * LROWS + c * 32 + v * 8) = o4[v];
        }
        int node = b * 64 + r;
        if (node < n) {
            #pragma unroll
            for (int v = 0; v < 4; v++)
                *(short8*)((char*)zout + (size_t)node * 256u + (unsigned)c * 64u + v * 16u) = o4[v];
        }
    }
    __syncthreads();

    // phase 4: GEMM
    int wv = tid >> 6, wl = tid & 63;
    int m = wl & 15, q = wl >> 4;
    short8 B[2][4];
    float bb[2];
    #pragma unroll
    for (int cc = 0; cc < 2; cc++) {
        int c2 = wv * 2 + cc;
        const short* wp = (const short*)Wb + (c2 * 16 + m) * 128 + q * 8;
        B[cc][0] = *(const short8*)(wp);
        B[cc][1] = *(const short8*)(wp + 32);
        B[cc][2] = *(const short8*)(wp + 64);
        B[cc][3] = *(const short8*)(wp + 96);
        bb[cc] = bias[c2 * 16 + m];
    }
    #pragma unroll
    for (int st = 0; st < 4; ++st) {
        const short* ap = lt + (st * 16 + m) * LROWS + q * 8;
        short8 a0 = *(const short8*)(ap);
        short8 a1 = *(const short8*)(ap + 32);
        short8 a2 = *(const short8*)(ap + 64);
        short8 a3 = *(const short8*)(ap + 96);
        f32x4 acc2[2];
        #pragma unroll
        for (int cc = 0; cc < 2; cc++) acc2[cc] = (f32x4){0.f, 0.f, 0.f, 0.f};
        #pragma unroll
        for (int cc = 0; cc < 2; cc++) {
            acc2[cc] = __builtin_amdgcn_mfma_f32_16x16x32_bf16(a0, B[cc][0], acc2[cc], 0, 0, 0);
            acc2[cc] = __builtin_amdgcn_mfma_f32_16x16x32_bf16(a1, B[cc][1], acc2[cc], 0, 0, 0);
            acc2[cc] = __builtin_amdgcn_mfma_f32_16x16x32_bf16(a2, B[cc][2], acc2[cc], 0, 0, 0);
            acc2[cc] = __builtin_amdgcn_mfma_f32_16x16x32_bf16(a3, B[cc][3], acc2[cc], 0, 0, 0);
        }
        int row0 = b * 64 + st * 16 + q * 4;
        #pragma unroll
        for (int cc = 0; cc < 2; cc++) {
            int col = (wv * 2 + cc) * 16 + m;
            #pragma unroll
            for (int r = 0; r < 4; r++) {
                int nd = row0 + r;
                if (nd < n) out[(size_t)nd * 128 + col] = acc2[cc][r] + bb[cc];
            }
        }
    }
}

__global__ __launch_bounds__(256) void fused_agg_gemm2(
        const int* __restrict__ ebuf, const int* __restrict__ bcur,
        const ushort4* __restrict__ zin4, const unsigned short* __restrict__ Wb,
        const float* __restrict__ w2b1, const float* __restrict__ bias2,
        float* __restrict__ out, int n) {
    __shared__ __align__(16) float acc[64 * ACCW];
    __shared__ int ebuf_s[ESCAP];
    __shared__ int deg_s[64];
    __shared__ int scur;
    short* lt = (short*)acc;

    int tid = threadIdx.x;
    int b = blockIdx.x;
    int cb = b >> 2, qq = b & 3;
    int e0 = cb * CAP;
    int cnt = min(bcur[cb], CAP);
    const char* zb = (const char*)zin4;

    {
        int r = tid >> 2, c = tid & 3;
        int node = b * 64 + r;
        float* ar = acc + r * ACCW + c * 32;
        if (node < n) {
            const short8* xp = (const short8*)(zb + (size_t)node * 256u + (unsigned)c * 64u);
            #pragma unroll
            for (int v = 0; v < 4; v++) {
                short8 u = xp[v];
                #pragma unroll
                for (int t2 = 0; t2 < 8; t2++) ar[v * 8 + t2] = bf2f((unsigned short)u[t2]);
            }
        } else {
            #pragma unroll
            for (int i = 0; i < 32; i++) ar[i] = 0.f;
        }
    }
    if (tid < 64) deg_s[tid] = 0;
    if (tid == 0) scur = 0;
    __syncthreads();

    for (int e = tid; e < cnt; e += 256) {
        int code = ebuf[e0 + e];
        if (((code >> 6) & 3) == qq) {
            int p = atomicAdd(&scur, 1);
            if (p < ESCAP) {
                ebuf_s[p] = code;
                atomicAdd(&deg_s[code & 63], 1);
            }
        }
    }
    __syncthreads();
    int kept = min(scur, ESCAP);
    int kp = (kept + 31) & ~31;
    for (int i = kept + tid; i < kp; i += 256) ebuf_s[i] = (n << 8);
    __syncthreads();

    int w = tid >> 6, l = tid & 63;
    unsigned lby = (unsigned)l * 4u;
    for (int base = w * 8; base < kp; base += 32) {
        int code[8]; unsigned val[8];
        #pragma unroll
        for (int j = 0; j < 8; j++) code[j] = ebuf_s[base + j];
        #pragma unroll
        for (int j = 0; j < 8; j++) {
            unsigned off = (((unsigned)code[j]) >> 8) * 256u + lby;
            val[j] = *(const unsigned*)(zb + off);
        }
        #pragma unroll
        for (int j = 0; j < 8; j++) {
            int d = code[j] & 63;
            float* ap2 = acc + d * ACCW + 2 * l;
            union { unsigned u; float f; } lo, hi;
            lo.u = val[j] << 16;
            hi.u = val[j] & 0xffff0000u;
            atomicAdd(ap2, lo.f);
            atomicAdd(ap2 + 1, hi.f);
        }
    }
    __syncthreads();

    {
        int r = tid >> 2, c = tid & 3;
        float fv[32];
        const float* ar = acc + r * ACCW + c * 32;
        #pragma unroll
        for (int i = 0; i < 32; i++) fv[i] = ar[i];
        __syncthreads();
        #pragma unroll
        for (int v = 0; v < 4; v++) {
            short8 o;
            #pragma unroll
            for (int t2 = 0; t2 < 8; t2++) o[t2] = (short)f2b(fv[v * 8 + t2]);
            *(short8*)(lt + r * LROWS + c * 32 + v * 8) = o;
        }
    }
    __syncthreads();

    int wv = tid >> 6, wl = tid & 63;
    int m = wl & 15, q = wl >> 4;
    short8 B[2][4];
    float wb2[2], bb2[2];
    #pragma unroll
    for (int cc = 0; cc < 2; cc++) {
        int c2 = wv * 2 + cc;
        const short* wp = (const short*)Wb + (c2 * 16 + m) * 128 + q * 8;
        B[cc][0] = *(const short8*)(wp);
        B[cc][1] = *(const short8*)(wp + 32);
        B[cc][2] = *(const short8*)(wp + 64);
        B[cc][3] = *(const short8*)(wp + 96);
        wb2[cc] = w2b1[c2 * 16 + m];
        bb2[cc] = bias2[c2 * 16 + m];
    }
    #pragma unroll
    for (int st = 0; st < 4; ++st) {
        const short* ap = lt + (st * 16 + m) * LROWS + q * 8;
        short8 a0 = *(const short8*)(ap);
        short8 a1 = *(const short8*)(ap + 32);
        short8 a2 = *(const short8*)(ap + 64);
        short8 a3 = *(const short8*)(ap + 96);
        f32x4 acc2[2];
        #pragma unroll
        for (int cc = 0; cc < 2; cc++) acc2[cc] = (f32x4){0.f, 0.f, 0.f, 0.f};
        #pragma unroll
        for (int cc = 0; cc < 2; cc++) {
            acc2[cc] = __builtin_amdgcn_mfma_f32_16x16x32_bf16(a0, B[cc][0], acc2[cc], 0, 0, 0);
            acc2[cc] = __builtin_amdgcn_mfma_f32_16x16x32_bf16(a1, B[cc][1], acc2[cc], 0, 0, 0);
            acc2[cc] = __builtin_amdgcn_mfma_f32_16x16x32_bf16(a2, B[cc][2], acc2[cc], 0, 0, 0);
            acc2[cc] = __builtin_amdgcn_mfma_f32_16x16x32_bf16(a3, B[cc][3], acc2[cc], 0, 0, 0);
        }
        int row0 = b * 64 + st * 16 + q * 4;
        #pragma unroll
        for (int cc = 0; cc < 2; cc++) {
            int col = (wv * 2 + cc) * 16 + m;
            #pragma unroll
            for (int r = 0; r < 4; r++) {
                int nd = row0 + r;
                if (nd < n) {
                    float degf = (float)(1 + deg_s[st * 16 + q * 4 + r]);
                    out[(size_t)nd * 128 + col] = acc2[cc][r] + degf * wb2[cc] + bb2[cc];
                }
            }
        }
    }
}

// ---------------- launch ----------------

extern "C" void kernel_launch(void* const* d_in, const int* in_sizes, int n_in,
                              void* d_out, int out_size, void* d_ws, size_t ws_size,
                              hipStream_t stream) {
    const float* x  = (const float*)d_in[0];
    const int*   ei = (const int*)d_in[1];
    const float* W1 = (const float*)d_in[2];
    const float* b1 = (const float*)d_in[3];
    const float* W2 = (const float*)d_in[4];
    const float* b2 = (const float*)d_in[5];

    const int n = in_sizes[0] / DFEAT;   // 100000
    const int E = in_sizes[1] / 2;       // 1600000
    const int* src = ei;
    const int* dst = ei + E;
    const int nbuckets = (n + 255) >> BSHIFT;         // 391 coarse buckets

    float* out = (float*)d_out;
    float* hid = out + (size_t)n * DFEAT;

    // xb lives in the dead `out` region (fp32 out = 51.2 MB >= 25.6 MB bf16
    // + zero row; out is only written by fused_agg_gemm2, after xb is dead).
    unsigned short* xb = (unsigned short*)out;

    // workspace: z1b(+zero row) | ebuf | bcur | weights   (~38.5 MB)
    char* w = (char*)d_ws;
    const size_t szB = (size_t)n * DFEAT * sizeof(unsigned short);   // 25.6 MB
    const size_t szB1 = szB + 4096;                                  // + zero row
    unsigned short* z1b = (unsigned short*)w;
    int* ebuf = (int*)(w + szB1);                 // nbuckets*CAP ints = 12.8 MB
    int* bcur = (int*)(ebuf + (size_t)nbuckets * CAP);
    char* wp = (char*)(bcur + NB_MAX);
    unsigned short* Wb1 = (unsigned short*)wp;
    unsigned short* Wcb = Wb1 + DFEAT * DFEAT;
    float* w2b1 = (float*)(Wcb + DFEAT * DFEAT);

    const int nscat = (E + 4095) / 4096;            // 391
    const int cast_blocks = (n * 32 + 255) / 256;   // 12500
    hipMemsetAsync(bcur, 0, nbuckets * sizeof(int), stream);
    scatter_cast_prep<<<nscat + 64 + cast_blocks, 256, 0, stream>>>(
        src, dst, bcur, ebuf, E, nscat, nbuckets, x, xb, n * 32, n,
        W1, W2, b1, Wb1, Wcb, w2b1);

    const int nblk = (n + 63) / 64;   // 1563
    fused_agg_gemm1<<<nblk, 256, 0, stream>>>(
        ebuf, bcur, (const ushort4*)xb, Wb1, b1, z1b, hid, n);
    fused_agg_gemm2<<<nblk, 256, 0, stream>>>(
        ebuf, bcur, (const ushort4*)z1b, Wcb, w2b1, b2, out, n);
}

// Round 11
// 327.118 us; speedup vs baseline: 7.8822x; 7.8822x over previous
//
#include <hip/hip_runtime.h>

// GIN 2-layer via linearity:
//   z1 = (I+A)x ; hid = z1@W1^T + b1
//   z2 = (I+A)z1 ; out = z2@(W2W1)^T + (1+deg)*(W2b1) + b2
// Round 11: R10 (LDS-atomic accumulate) was a 7.9x disaster (3.1M bank
// conflicts, 1240us/agg) -> full revert to R7's measured-best structure
// (326us). One isolated change: csr_prep parallelized 4x -- one block per
// 64-node quarter-bucket (1564 blocks vs 391), each quarter owning esrc
// region e0 + q*CAP/4 (cap 2048, 32-sigma). agg kernels byte-identical R7.

#define DFEAT 128
#define BSHIFT 8
#define NB_MAX 512
#define CAP 8192   // coarse bucket capacity; mean 4096, 64-sigma safe
#define QCAP 2048  // per-quarter esrc capacity; mean 1024, 32-sigma
#define LROWS 136  // LDS row stride in shorts (272 B)
#define AGG_BLOCKS 2048

typedef __attribute__((ext_vector_type(8))) short short8;
typedef __attribute__((ext_vector_type(4))) float f32x4;

__device__ __forceinline__ float bf2f(unsigned short u) {
    union { unsigned int i; float f; } c;
    c.i = ((unsigned int)u) << 16;
    return c.f;
}
__device__ __forceinline__ unsigned short f2b(float f) {
    union { float f; unsigned int i; } c;
    c.f = f;
    unsigned int u = c.i;
    u = (u + 0x7FFFu + ((u >> 16) & 1u)) >> 16;   // RNE
    return (unsigned short)u;
}

// ---------------- fused bucket_scatter + cast_bf16 (R7 verbatim) -----------

__global__ __launch_bounds__(256) void scatter_cast(const int* __restrict__ src,
                                                    const int* __restrict__ dst,
                                                    int* __restrict__ bcur,
                                                    int* __restrict__ ebuf, int E,
                                                    int nscat,
                                                    const float* __restrict__ x,
                                                    unsigned short* __restrict__ xb,
                                                    int total4, int nzero) {
    int tid = threadIdx.x;
    if (blockIdx.x >= nscat) {
        int i = (blockIdx.x - nscat) * 256 + tid;
        if (i < total4) {
            float4 v = ((const float4*)x)[i];
            ushort4 o;
            o.x = f2b(v.x); o.y = f2b(v.y); o.z = f2b(v.z); o.w = f2b(v.w);
            ((ushort4*)xb)[i] = o;
        }
        if (blockIdx.x == nscat && tid < 32)   // zero-row at index nzero
            ((ushort4*)xb)[(size_t)nzero * 32 + tid] = make_ushort4(0, 0, 0, 0);
        return;
    }
    __shared__ int lh[NB_MAX];
    for (int i = tid; i < NB_MAX; i += 256) lh[i] = 0;
    __syncthreads();
    int e0 = blockIdx.x * 4096;
    int e1 = min(e0 + 4096, E);
    int s[16], d[16];
    #pragma unroll
    for (int j = 0; j < 16; j++) {
        int e = e0 + tid + 256 * j;
        if (e < e1) { s[j] = src[e]; d[j] = dst[e]; atomicAdd(&lh[d[j] >> BSHIFT], 1); }
    }
    __syncthreads();
    for (int i = tid; i < NB_MAX; i += 256) {
        int c = lh[i];
        lh[i] = c ? (i * CAP + atomicAdd(&bcur[i], c)) : 0;  // absolute base
    }
    __syncthreads();
    #pragma unroll
    for (int j = 0; j < 16; j++) {
        int e = e0 + tid + 256 * j;
        if (e < e1) {
            int b = d[j] >> BSHIFT;
            int p = atomicAdd(&lh[b], 1);
            if (p < (b + 1) * CAP) ebuf[p] = (s[j] << 8) | (d[j] & 255);
        }
    }
}

// ---------------- quarter-bucket CSR build + weight prep ----------------
// blocks [0,nq): quarter q=b&3 of coarse bucket cb=b>>2. Reads the bucket's
// edges, keeps its 64-node quarter, hist/scan/scatter into esrc region
// e0 + q*QCAP. blocks [nq,nq+64): weight prep (2 rows each).

__global__ __launch_bounds__(256) void csr_prep_q(const int* __restrict__ ebuf,
                                                  const int* __restrict__ bcur,
                                                  int2* __restrict__ rpse,
                                                  int* __restrict__ esrc, int n, int nq,
                                                  const float* __restrict__ W1,
                                                  const float* __restrict__ W2,
                                                  const float* __restrict__ b1,
                                                  unsigned short* __restrict__ Wb1,
                                                  unsigned short* __restrict__ Wcb,
                                                  float* __restrict__ w2b1) {
    int tid = threadIdx.x;
    if (blockIdx.x >= nq) {
        __shared__ float red[256];
        int bb = blockIdx.x - nq;
        int i = bb * 2 + (tid >> 7);
        int j = tid & 127;
        float s = 0.f;
        #pragma unroll 4
        for (int k = 0; k < 128; k++) s += W2[i * 128 + k] * W1[k * 128 + j];
        Wcb[i * 128 + j] = f2b(s);
        Wb1[i * 128 + j] = f2b(W1[i * 128 + j]);
        red[tid] = W2[i * 128 + j] * b1[j];
        __syncthreads();
        if (j == 0) {
            float t = 0.f;
            for (int k = 0; k < 128; k++) t += red[tid + k];
            w2b1[i] = t;
        }
        return;
    }
    __shared__ int hist[64];
    __shared__ int excl_s[64];
    int b = blockIdx.x, cb = b >> 2, qq = b & 3;
    int e0 = cb * CAP;
    int cnt = min(bcur[cb], CAP);
    int qbase = e0 + qq * QCAP;
    if (tid < 64) hist[tid] = 0;
    __syncthreads();
    for (int e = tid; e < cnt; e += 256) {
        int d = ebuf[e0 + e] & 255;
        if ((d >> 6) == qq) atomicAdd(&hist[d & 63], 1);
    }
    __syncthreads();
    if (tid < 64) {
        int v = hist[tid];
        int inc = v;
        #pragma unroll
        for (int off = 1; off < 64; off <<= 1) {
            int u = __shfl_up(inc, off, 64);
            if (tid >= off) inc += u;
        }
        int excl = inc - v;
        excl_s[tid] = excl;
        int node = cb * 256 + qq * 64 + tid;
        if (node < n) rpse[node] = make_int2(qbase + excl, qbase + excl + v);
    }
    __syncthreads();
    if (tid < 64) hist[tid] = excl_s[tid];
    __syncthreads();
    for (int e = tid; e < cnt; e += 256) {
        int code = ebuf[e0 + e];
        int d = code & 255;
        if ((d >> 6) == qq) {
            int p = atomicAdd(&hist[d & 63], 1);
            esrc[qbase + p] = ((unsigned)code) >> 8;
        }
    }
}

// ---------------- fused aggregation + GEMM (persistent, pipelined; R7) -----

// layer 1: writes z1 (bf16, global, + zero row) + hid = z1@W1^T + b1
__global__ __launch_bounds__(256) void fused_agg_gemm1(
        const ushort4* __restrict__ zin4, const int2* __restrict__ rpse,
        const int* __restrict__ esrc, const unsigned short* __restrict__ Wb,
        const float* __restrict__ bias, unsigned short* __restrict__ zout,
        float* __restrict__ out, int n, int ntiles) {
    __shared__ __align__(16) short lt[16 * LROWS];
    int w = threadIdx.x >> 6;
    int wl = threadIdx.x & 63;
    int gl = wl & 15, q = wl >> 4;
    int gbase = wl & 48;
    unsigned lb = (unsigned)gl * 16u;
    int lrow = w * 4 + q;
    const char* zb = (const char*)zin4;
    const int stride = gridDim.x;

    if (blockIdx.x == 0 && threadIdx.x < 16) {   // zero-row for layer-2 gathers
        short8 z8;
        #pragma unroll
        for (int t = 0; t < 8; t++) z8[t] = 0;
        *(short8*)((char*)zout + (unsigned)n * 256u + threadIdx.x * 16) = z8;
    }

    float bb[2];
    #pragma unroll
    for (int cc = 0; cc < 2; cc++) bb[cc] = bias[(w * 2 + cc) * 16 + gl];

    int t = blockIdx.x;
    int node = t * 16 + lrow;
    int2 se = make_int2(0, 0);
    if (t < ntiles && node < n) se = rpse[node];
    int deg0 = se.y - se.x;
    int ei0 = (t < ntiles && node < n && gl < deg0) ? esrc[se.x + gl] : n;
    int ei1 = (t < ntiles && node < n && gl + 16 < deg0) ? esrc[se.x + gl + 16] : n;

    for (; t < ntiles; ) {
        int tn = t + stride;
        int node_n = tn * 16 + lrow;
        int2 se_n = make_int2(0, 0);
        if (tn < ntiles && node_n < n) se_n = rpse[node_n];   // issue early

        int node_c = node < n ? node : n;
        float a[8];
        short8 sv = *(const short8*)(zb + (unsigned)node_c * 256u + lb);
        #pragma unroll
        for (int tt = 0; tt < 8; tt++) a[tt] = bf2f((unsigned short)sv[tt]);

        unsigned off[16];
        short8 vv[16];
        #pragma unroll
        for (int k = 0; k < 16; k++)
            off[k] = (unsigned)__shfl(ei0, gbase + k) * 256u + lb;
        #pragma unroll
        for (int k = 0; k < 16; k++) vv[k] = *(const short8*)(zb + off[k]);

        int deg_n = se_n.y - se_n.x;
        int ei0_n = n, ei1_n = n;
        if (tn < ntiles && node_n < n) {
            if (gl < deg_n)      ei0_n = esrc[se_n.x + gl];
            if (gl + 16 < deg_n) ei1_n = esrc[se_n.x + gl + 16];
        }

        #pragma unroll
        for (int k = 0; k < 16; k++) {
            #pragma unroll
            for (int tt = 0; tt < 8; tt++) a[tt] += bf2f((unsigned short)vv[k][tt]);
        }
        int deg = se.y - se.x;
        if (deg > 16) {
            unsigned o2[16];
            short8 v2[16];
            #pragma unroll
            for (int k = 0; k < 16; k++)
                o2[k] = (unsigned)__shfl(ei1, gbase + k) * 256u + lb;
            #pragma unroll
            for (int k = 0; k < 16; k++) v2[k] = *(const short8*)(zb + o2[k]);
            #pragma unroll
            for (int k = 0; k < 16; k++) {
                #pragma unroll
                for (int tt = 0; tt < 8; tt++) a[tt] += bf2f((unsigned short)v2[k][tt]);
            }
        }
        for (int rb = 32; rb < deg; rb += 16) {   // rare deg > 32 tail
            int eidx = (rb + gl < deg) ? esrc[se.x + rb + gl] : n;
            unsigned o2[16];
            short8 v2[16];
            #pragma unroll
            for (int k = 0; k < 16; k++)
                o2[k] = (unsigned)__shfl(eidx, gbase + k) * 256u + lb;
            #pragma unroll
            for (int k = 0; k < 16; k++) v2[k] = *(const short8*)(zb + o2[k]);
            #pragma unroll
            for (int k = 0; k < 16; k++) {
                #pragma unroll
                for (int tt = 0; tt < 8; tt++) a[tt] += bf2f((unsigned short)v2[k][tt]);
            }
        }

        short8 o;
        #pragma unroll
        for (int tt = 0; tt < 8; tt++) o[tt] = (short)f2b(a[tt]);
        *(short8*)((char*)lt + lrow * (LROWS * 2) + lb) = o;
        if (node < n) *(short8*)((char*)zout + (unsigned)node * 256u + lb) = o;
        __syncthreads();

        int m = gl;
        const short* ap = lt + m * LROWS + q * 8;
        short8 a0 = *(const short8*)(ap);
        short8 a1 = *(const short8*)(ap + 32);
        short8 a2 = *(const short8*)(ap + 64);
        short8 a3 = *(const short8*)(ap + 96);
        f32x4 acc[2];
        #pragma unroll
        for (int cc = 0; cc < 2; cc++) acc[cc] = (f32x4){0.f, 0.f, 0.f, 0.f};
        #pragma unroll
        for (int cc = 0; cc < 2; cc++) {
            int c = w * 2 + cc;
            const short* wp = (const short*)Wb + (c * 16 + m) * 128 + q * 8;
            short8 b0 = *(const short8*)(wp);
            short8 b1v = *(const short8*)(wp + 32);
            short8 b2v = *(const short8*)(wp + 64);
            short8 b3v = *(const short8*)(wp + 96);
            acc[cc] = __builtin_amdgcn_mfma_f32_16x16x32_bf16(a0, b0, acc[cc], 0, 0, 0);
            acc[cc] = __builtin_amdgcn_mfma_f32_16x16x32_bf16(a1, b1v, acc[cc], 0, 0, 0);
            acc[cc] = __builtin_amdgcn_mfma_f32_16x16x32_bf16(a2, b2v, acc[cc], 0, 0, 0);
            acc[cc] = __builtin_amdgcn_mfma_f32_16x16x32_bf16(a3, b3v, acc[cc], 0, 0, 0);
        }
        int row0 = t * 16 + q * 4;
        #pragma unroll
        for (int cc = 0; cc < 2; cc++) {
            int col = (w * 2 + cc) * 16 + m;
            #pragma unroll
            for (int r = 0; r < 4; r++) {
                int nd = row0 + r;
                if (nd < n) out[(size_t)nd * 128 + col] = acc[cc][r] + bb[cc];
            }
        }
        __syncthreads();

        se = se_n; ei0 = ei0_n; ei1 = ei1_n; node = node_n; t = tn;
    }
}

// layer 2: z2 never materialized; out = z2@Wc^T + (1+deg)*w2b1 + b2
__global__ __launch_bounds__(256) void fused_agg_gemm2(
        const ushort4* __restrict__ zin4, const int2* __restrict__ rpse,
        const int* __restrict__ esrc, const unsigned short* __restrict__ Wb,
        const float* __restrict__ w2b1, const float* __restrict__ bias2,
        float* __restrict__ out, int n, int ntiles) {
    __shared__ __align__(16) short lt[16 * LROWS];
    int w = threadIdx.x >> 6;
    int wl = threadIdx.x & 63;
    int gl = wl & 15, q = wl >> 4;
    int gbase = wl & 48;
    unsigned lb = (unsigned)gl * 16u;
    int lrow = w * 4 + q;
    const char* zb = (const char*)zin4;
    const int stride = gridDim.x;

    float wb2[2], bb2[2];
    #pragma unroll
    for (int cc = 0; cc < 2; cc++) {
        int col = (w * 2 + cc) * 16 + gl;
        wb2[cc] = w2b1[col];
        bb2[cc] = bias2[col];
    }

    int t = blockIdx.x;
    int node = t * 16 + lrow;
    int2 se = make_int2(0, 0);
    if (t < ntiles && node < n) se = rpse[node];
    int deg0 = se.y - se.x;
    int ei0 = (t < ntiles && node < n && gl < deg0) ? esrc[se.x + gl] : n;
    int ei1 = (t < ntiles && node < n && gl + 16 < deg0) ? esrc[se.x + gl + 16] : n;

    for (; t < ntiles; ) {
        int tn = t + stride;
        int node_n = tn * 16 + lrow;
        int2 se_n = make_int2(0, 0);
        if (tn < ntiles && node_n < n) se_n = rpse[node_n];   // issue early

        int node_c = node < n ? node : n;
        float a[8];
        short8 sv = *(const short8*)(zb + (unsigned)node_c * 256u + lb);
        #pragma unroll
        for (int tt = 0; tt < 8; tt++) a[tt] = bf2f((unsigned short)sv[tt]);

        unsigned off[16];
        short8 vv[16];
        #pragma unroll
        for (int k = 0; k < 16; k++)
            off[k] = (unsigned)__shfl(ei0, gbase + k) * 256u + lb;
        #pragma unroll
        for (int k = 0; k < 16; k++) vv[k] = *(const short8*)(zb + off[k]);

        int deg_n = se_n.y - se_n.x;
        int ei0_n = n, ei1_n = n;
        if (tn < ntiles && node_n < n) {
            if (gl < deg_n)      ei0_n = esrc[se_n.x + gl];
            if (gl + 16 < deg_n) ei1_n = esrc[se_n.x + gl + 16];
        }

        #pragma unroll
        for (int k = 0; k < 16; k++) {
            #pragma unroll
            for (int tt = 0; tt < 8; tt++) a[tt] += bf2f((unsigned short)vv[k][tt]);
        }
        int deg = se.y - se.x;
        if (deg > 16) {
            unsigned o2[16];
            short8 v2[16];
            #pragma unroll
            for (int k = 0; k < 16; k++)
                o2[k] = (unsigned)__shfl(ei1, gbase + k) * 256u + lb;
            #pragma unroll
            for (int k = 0; k < 16; k++) v2[k] = *(const short8*)(zb + o2[k]);
            #pragma unroll
            for (int k = 0; k < 16; k++) {
                #pragma unroll
                for (int tt = 0; tt < 8; tt++) a[tt] += bf2f((unsigned short)v2[k][tt]);
            }
        }
        for (int rb = 32; rb < deg; rb += 16) {
            int eidx = (rb + gl < deg) ? esrc[se.x + rb + gl] : n;
            unsigned o2[16];
            short8 v2[16];
            #pragma unroll
            for (int k = 0; k < 16; k++)
                o2[k] = (unsigned)__shfl(eidx, gbase + k) * 256u + lb;
            #pragma unroll
            for (int k = 0; k < 16; k++) v2[k] = *(const short8*)(zb + o2[k]);
            #pragma unroll
            for (int k = 0; k < 16; k++) {
                #pragma unroll
                for (int tt = 0; tt < 8; tt++) a[tt] += bf2f((unsigned short)v2[k][tt]);
            }
        }

        short8 o;
        #pragma unroll
        for (int tt = 0; tt < 8; tt++) o[tt] = (short)f2b(a[tt]);
        *(short8*)((char*)lt + lrow * (LROWS * 2) + lb) = o;
        __syncthreads();

        int m = gl;
        const short* ap = lt + m * LROWS + q * 8;
        short8 a0 = *(const short8*)(ap);
        short8 a1 = *(const short8*)(ap + 32);
        short8 a2 = *(const short8*)(ap + 64);
        short8 a3 = *(const short8*)(ap + 96);
        f32x4 acc[2];
        #pragma unroll
        for (int cc = 0; cc < 2; cc++) acc[cc] = (f32x4){0.f, 0.f, 0.f, 0.f};
        #pragma unroll
        for (int cc = 0; cc < 2; cc++) {
            int c = w * 2 + cc;
            const short* wp = (const short*)Wb + (c * 16 + m) * 128 + q * 8;
            short8 b0 = *(const short8*)(wp);
            short8 b1v = *(const short8*)(wp + 32);
            short8 b2v = *(const short8*)(wp + 64);
            short8 b3v = *(const short8*)(wp + 96);
            acc[cc] = __builtin_amdgcn_mfma_f32_16x16x32_bf16(a0, b0, acc[cc], 0, 0, 0);
            acc[cc] = __builtin_amdgcn_mfma_f32_16x16x32_bf16(a1, b1v, acc[cc], 0, 0, 0);
            acc[cc] = __builtin_amdgcn_mfma_f32_16x16x32_bf16(a2, b2v, acc[cc], 0, 0, 0);
            acc[cc] = __builtin_amdgcn_mfma_f32_16x16x32_bf16(a3, b3v, acc[cc], 0, 0, 0);
        }
        int row0 = t * 16 + q * 4;
        float degf[4];
        #pragma unroll
        for (int r = 0; r < 4; r++) {
            int nd = row0 + r;
            if (nd < n) {
                int2 s2 = rpse[nd];
                degf[r] = (float)(1 + s2.y - s2.x);
            } else degf[r] = 0.f;
        }
        #pragma unroll
        for (int cc = 0; cc < 2; cc++) {
            int col = (w * 2 + cc) * 16 + m;
            #pragma unroll
            for (int r = 0; r < 4; r++) {
                int nd = row0 + r;
                if (nd < n) out[(size_t)nd * 128 + col] = acc[cc][r] + degf[r] * wb2[cc] + bb2[cc];
            }
        }
        __syncthreads();

        se = se_n; ei0 = ei0_n; ei1 = ei1_n; node = node_n; t = tn;
    }
}

// ---------------- launch ----------------

extern "C" void kernel_launch(void* const* d_in, const int* in_sizes, int n_in,
                              void* d_out, int out_size, void* d_ws, size_t ws_size,
                              hipStream_t stream) {
    const float* x  = (const float*)d_in[0];
    const int*   ei = (const int*)d_in[1];
    const float* W1 = (const float*)d_in[2];
    const float* b1 = (const float*)d_in[3];
    const float* W2 = (const float*)d_in[4];
    const float* b2 = (const float*)d_in[5];

    const int n = in_sizes[0] / DFEAT;   // 100000
    const int E = in_sizes[1] / 2;       // 1600000
    const int* src = ei;
    const int* dst = ei + E;
    const int nbuckets = (n + 255) >> BSHIFT;   // 391

    float* out = (float*)d_out;
    float* hid = out + (size_t)n * DFEAT;

    // xb lives in the dead `out` region (fp32 out = 51.2 MB >= 25.6 MB bf16
    // + zero row; out is only written by fused_agg_gemm2, after xb is dead).
    unsigned short* xb = (unsigned short*)out;

    // workspace: z1b(+zero row) | ebuf | esrc | rpse | bcur | weights
    char* w = (char*)d_ws;
    const size_t szB = (size_t)n * DFEAT * sizeof(unsigned short);   // 25.6 MB
    const size_t szB1 = szB + 4096;                                  // + zero row
    unsigned short* z1b = (unsigned short*)w;
    int* ebuf = (int*)(w + szB1);                 // nbuckets*CAP ints = 12.8 MB
    int* esrc = (int*)(w + szB1 + szB);           // nbuckets*CAP = 12.8 MB
    int2* rpse = (int2*)(esrc + (size_t)nbuckets * CAP);
    int* bcur = (int*)(rpse + n);
    char* wp = (char*)(bcur + NB_MAX);
    unsigned short* Wb1 = (unsigned short*)wp;
    unsigned short* Wcb = Wb1 + DFEAT * DFEAT;
    float* w2b1 = (float*)(Wcb + DFEAT * DFEAT);

    const int nscat = (E + 4095) / 4096;            // 391
    const int cast_blocks = (n * 32 + 255) / 256;   // 12500
    hipMemsetAsync(bcur, 0, nbuckets * sizeof(int), stream);
    scatter_cast<<<nscat + cast_blocks, 256, 0, stream>>>(
        src, dst, bcur, ebuf, E, nscat, x, xb, n * 32, n);

    const int nq = nbuckets * 4;   // 1564 quarter blocks
    csr_prep_q<<<nq + 64, 256, 0, stream>>>(
        ebuf, bcur, rpse, esrc, n, nq, W1, W2, b1, Wb1, Wcb, w2b1);

    const int ntiles = (n + 15) / 16;   // 6250
    fused_agg_gemm1<<<AGG_BLOCKS, 256, 0, stream>>>(
        (const ushort4*)xb, rpse, esrc, Wb1, b1, z1b, hid, n, ntiles);
    fused_agg_gemm2<<<AGG_BLOCKS, 256, 0, stream>>>(
        (const ushort4*)z1b, rpse, esrc, Wcb, w2b1, b2, out, n, ntiles);
}